// Round 13
// baseline (486.926 us; speedup 1.0000x reference)
//
#include <hip/hip_runtime.h>

typedef unsigned short ushort_t;
typedef __attribute__((ext_vector_type(8))) short bf16x8;
typedef __attribute__((ext_vector_type(4))) float f32x4;

// ---------------- problem constants ----------------
constexpr int Nn = 100000;   // nodes
constexpr int Ee = 1600000;  // edges
// IN = 256, H = 64, NH = 4 (layer1 heads), head 4 = output head

constexpr int NBUCK = 391;   // ceil(Nn/256) node buckets of 256
constexpr int BCAP  = 6144;  // per-bucket capacity (mean 4096, sigma ~64)
constexpr int CH3   = 8192;  // edges per block in bin pass
constexpr int NBLK3 = (Ee + CH3 - 1) / CH3;  // 196

// ---------------- workspace layout (bytes) ----------------
constexpr size_t O_ROWPS  = 0;              // (Nn+1) int
constexpr size_t O_ROWPD  = 400512;         // (Nn+1) int
constexpr size_t O_BOFF   = 801024;         // 2*392 int
constexpr size_t O_GCUR   = 805120;         // 2*391 int
constexpr size_t O_CSRDST = 809216;         // Ee int
constexpr size_t O_CSCSRC = 7209216;        // Ee int
constexpr size_t O_FTB1   = 13609216;       // Nn*256 bf16 (51.2MB)
constexpr size_t O_FTB2   = 64809216;       // Nn*64 bf16
constexpr size_t O_LASTB  = 77609216;       // Nn*256 bf16 (51.2MB)
constexpr size_t O_P4     = 180009216;      // Nn*4 float4 (6.4MB) {a1,m,1/S}
constexpr size_t O_P2     = 196809216;      // Nn float4 (1.6MB)
constexpr size_t O_M4     = 205609216;      // Nn*4 f32
constexpr size_t O_A14    = 208809216;      // Nn*4 f32
constexpr size_t O_A24    = 210409216;      // Nn*4 f32
constexpr size_t O_M2     = 212009216;      // Nn f32
constexpr size_t O_A12    = 212810240;      // Nn f32
constexpr size_t O_A22    = 213210752;      // Nn f32
constexpr size_t O_OUT2   = 213611264;      // Nn*64 f32
constexpr size_t O_WT1    = 239211264;      // 256*256 bf16 (layer1 weights, [col][k])
constexpr size_t O_WT2    = 239342336;      // 64*256 bf16
constexpr size_t O_WTR    = 239375104;      // 64*256 bf16   end ~239.4MB
// aliases (lifetimes disjoint):
constexpr size_t O_BUFS   = O_FTB1;
constexpr size_t O_BUFD   = O_FTB1 + (size_t)NBUCK * BCAP * 8;

__device__ __forceinline__ ushort_t f2bf(float x) {
    unsigned u = __float_as_uint(x);
    unsigned r = (u + 0x7FFFu + ((u >> 16) & 1u)) >> 16;
    return (ushort_t)r;
}
__device__ __forceinline__ float bflo(unsigned u) { return __uint_as_float(u << 16); }
__device__ __forceinline__ float bfhi(unsigned u) { return __uint_as_float(u & 0xffff0000u); }

// ---------------- weight pre-transpose+convert: Wt[col][k] bf16 ----------------
__global__ void wcvt_k(const float* __restrict__ Wfc, const float* __restrict__ Wres,
                       ushort_t* __restrict__ Wt1, ushort_t* __restrict__ Wt2,
                       ushort_t* __restrict__ WtR) {
    int g = blockIdx.x * 256 + threadIdx.x;
    if (g < 65536) {
        int c = g >> 8, k = g & 255;
        Wt1[g] = f2bf(Wfc[(size_t)(c >> 6) * 16384 + k * 64 + (c & 63)]);
    } else if (g < 81920) {
        int q = g - 65536;
        int c = q >> 8, k = q & 255;
        Wt2[q] = f2bf(Wfc[4 * 16384 + k * 64 + c]);
    } else {
        int q = g - 81920;
        int c = q >> 8, k = q & 255;
        WtR[q] = f2bf(Wres[k * 64 + c]);
    }
}

// ---------------- P3: bin edges into node-range buckets (both orderings) ----------------
__global__ __launch_bounds__(256) void p3_bin_k(const int* __restrict__ src,
                                                const int* __restrict__ dst,
                                                int* __restrict__ gcur,
                                                int2* __restrict__ bufs,
                                                int2* __restrict__ bufd) {
    __shared__ int hs[NBUCK], hd[NBUCK], rs[NBUCK], rd[NBUCK];
    int t = threadIdx.x;
    for (int i = t; i < NBUCK; i += 256) { hs[i] = 0; hd[i] = 0; }
    __syncthreads();
    int e0 = blockIdx.x * CH3;
    int ne = min(CH3, Ee - e0);
    for (int i = t; i < ne; i += 256) {
        atomicAdd(&hs[src[e0 + i] >> 8], 1);
        atomicAdd(&hd[dst[e0 + i] >> 8], 1);
    }
    __syncthreads();
    for (int i = t; i < NBUCK; i += 256) {
        rs[i] = hs[i] ? atomicAdd(&gcur[i], hs[i]) : 0;
        rd[i] = hd[i] ? atomicAdd(&gcur[NBUCK + i], hd[i]) : 0;
        hs[i] = 0; hd[i] = 0;
    }
    __syncthreads();
    for (int i = t; i < ne; i += 256) {
        int s = src[e0 + i], d = dst[e0 + i];
        int bu = s >> 8;
        int pos = rs[bu] + atomicAdd(&hs[bu], 1);
        if (pos < BCAP) bufs[(size_t)bu * BCAP + pos] = make_int2(s, d);
        bu = d >> 8;
        pos = rd[bu] + atomicAdd(&hd[bu], 1);
        if (pos < BCAP) bufd[(size_t)bu * BCAP + pos] = make_int2(d, s);
    }
}

// ---------------- P2: scan bucket counts ----------------
__global__ void p2_scan_k(const int* __restrict__ gcur, int* __restrict__ boff,
                          int* __restrict__ rowps, int* __restrict__ rowpd) {
    __shared__ int sh[512];
    int t = threadIdx.x;
    const int* cnt = gcur + blockIdx.x * NBUCK;
    int* bo = boff + blockIdx.x * 392;
    int v = (t < NBUCK) ? min(cnt[t], BCAP) : 0;
    sh[t] = v;
    __syncthreads();
    for (int o = 1; o < 512; o <<= 1) {
        int x = (t >= o) ? sh[t - o] : 0;
        __syncthreads();
        sh[t] += x;
        __syncthreads();
    }
    if (t < NBUCK) bo[t] = sh[t] - v;
    if (t == NBUCK - 1) {
        bo[NBUCK] = sh[t];
        int* rp = blockIdx.x ? rowpd : rowps;
        rp[Nn] = sh[t];
    }
}

// ---------------- P4: per-bucket fill ----------------
__global__ __launch_bounds__(256) void p4_fill_k(const int* __restrict__ gcur,
                                                 const int* __restrict__ boff,
                                                 const int2* __restrict__ bufs,
                                                 const int2* __restrict__ bufd,
                                                 int* __restrict__ rowps,
                                                 int* __restrict__ rowpd,
                                                 int* __restrict__ csr_dst,
                                                 int* __restrict__ csc_src) {
    __shared__ int cnt[256], lofs[256], sc[256];
    int b = blockIdx.x, st = blockIdx.y;
    const int2* buf = (st ? bufd : bufs) + (size_t)b * BCAP;
    int base = boff[st * 392 + b];
    int total = min(gcur[st * NBUCK + b], BCAP);
    int* rowp = st ? rowpd : rowps;
    int* outv = st ? csc_src : csr_dst;
    int t = threadIdx.x, node0 = b << 8;
    cnt[t] = 0;
    __syncthreads();
    for (int i = t; i < total; i += 256) atomicAdd(&cnt[buf[i].x - node0], 1);
    __syncthreads();
    int v = cnt[t];
    sc[t] = v;
    __syncthreads();
    for (int o = 1; o < 256; o <<= 1) {
        int x = (t >= o) ? sc[t - o] : 0;
        __syncthreads();
        sc[t] += x;
        __syncthreads();
    }
    lofs[t] = sc[t] - v;
    if (node0 + t < Nn) rowp[node0 + t] = base + lofs[t];
    cnt[t] = 0;
    __syncthreads();
    for (int i = t; i < total; i += 256) {
        int2 p = buf[i];
        int k = p.x - node0;
        int r = atomicAdd(&cnt[k], 1);
        outv[base + lofs[k] + r] = p.y;
    }
}

// ---------------- MFMA GEMM: C[N, NPAN*BN] = A[N,256] @ Bt^T + bias (+add) ----------------
template <int ABF16, int BN, int NPAN, int WGM, int FUSEA, int ADD, int ELU, int BF16OUT>
__global__ __launch_bounds__(256) void mgemm_k(
    const float* __restrict__ Af, const ushort_t* __restrict__ Ab,
    const ushort_t* __restrict__ Bt, const float* __restrict__ bias,
    const float* __restrict__ addp,
    ushort_t* __restrict__ outb, float* __restrict__ outf, int ostride,
    const float* __restrict__ wl, const float* __restrict__ wr,
    const float* __restrict__ blp, const float* __restrict__ brp,
    float* __restrict__ a1, float* __restrict__ a2, int astride) {
    constexpr int MROWS = 128 / WGM;
    constexpr int MREP = MROWS / 16;
    constexpr int LDA = 40;  // shorts per LDS row (32 + 8 pad -> 2-way conflicts only)
    __shared__ short As[128 * LDA];
    __shared__ short Bs[NPAN][BN * LDA];
    int tid = threadIdx.x;
    int m0 = blockIdx.x * 128;
    int col0 = blockIdx.y * (BN * NPAN);
    int w = tid >> 6, l = tid & 63;
    int wr_ = w % WGM, wc = w / WGM;
    int lr = l & 15, lg = l >> 4;
    f32x4 acc[NPAN][MREP][4];
#pragma unroll
    for (int p = 0; p < NPAN; ++p)
#pragma unroll
        for (int m = 0; m < MREP; ++m)
#pragma unroll
            for (int n = 0; n < 4; ++n) acc[p][m][n] = (f32x4){0.f, 0.f, 0.f, 0.f};

    for (int kc = 0; kc < 8; ++kc) {
        int k0 = kc * 32;
        if (ABF16 == 0) {
            int r = tid >> 1, half = tid & 1;
            int grow = m0 + r;
            float4 f0, f1, f2, f3;
            if (grow < Nn) {
                const float4* ap = (const float4*)(Af + (size_t)grow * 256 + k0 + half * 16);
                f0 = ap[0]; f1 = ap[1]; f2 = ap[2]; f3 = ap[3];
            } else {
                f0 = f1 = f2 = f3 = make_float4(0.f, 0.f, 0.f, 0.f);
            }
            bf16x8 s0, s1;
            s0[0] = f2bf(f0.x); s0[1] = f2bf(f0.y); s0[2] = f2bf(f0.z); s0[3] = f2bf(f0.w);
            s0[4] = f2bf(f1.x); s0[5] = f2bf(f1.y); s0[6] = f2bf(f1.z); s0[7] = f2bf(f1.w);
            s1[0] = f2bf(f2.x); s1[1] = f2bf(f2.y); s1[2] = f2bf(f2.z); s1[3] = f2bf(f2.w);
            s1[4] = f2bf(f3.x); s1[5] = f2bf(f3.y); s1[6] = f2bf(f3.z); s1[7] = f2bf(f3.w);
            *(bf16x8*)&As[r * LDA + half * 16] = s0;
            *(bf16x8*)&As[r * LDA + half * 16 + 8] = s1;
        } else {
#pragma unroll
            for (int i = 0; i < 2; ++i) {
                int s = tid + i * 256, r = s >> 2, q = s & 3;
                int grow = m0 + r;
                int4 v = make_int4(0, 0, 0, 0);
                if (grow < Nn) v = *(const int4*)(Ab + (size_t)grow * 256 + k0 + q * 8);
                *(int4*)&As[r * LDA + q * 8] = v;
            }
        }
#pragma unroll
        for (int p = 0; p < NPAN; ++p)
#pragma unroll
            for (int i = 0; i < BN / 64; ++i) {
                int s = tid + i * 256, c = s >> 2, q = s & 3;
                int4 v = *(const int4*)(Bt + (size_t)(col0 + p * BN + c) * 256 + k0 + q * 8);
                *(int4*)&Bs[p][c * LDA + q * 8] = v;
            }
        __syncthreads();
        bf16x8 af[MREP];
#pragma unroll
        for (int m = 0; m < MREP; ++m)
            af[m] = *(const bf16x8*)&As[(wr_ * MROWS + m * 16 + lr) * LDA + lg * 8];
#pragma unroll
        for (int p = 0; p < NPAN; ++p) {
            bf16x8 bfr[4];
#pragma unroll
            for (int n = 0; n < 4; ++n)
                bfr[n] = *(const bf16x8*)&Bs[p][(wc * 64 + n * 16 + lr) * LDA + lg * 8];
#pragma unroll
            for (int m = 0; m < MREP; ++m)
#pragma unroll
                for (int n = 0; n < 4; ++n)
                    acc[p][m][n] = __builtin_amdgcn_mfma_f32_16x16x32_bf16(af[m], bfr[n], acc[p][m][n], 0, 0, 0);
        }
        __syncthreads();
    }

#pragma unroll
    for (int p = 0; p < NPAN; ++p) {
        int coln[4];
        float biasv[4], wlv[4] = {}, wrv[4] = {};
#pragma unroll
        for (int n = 0; n < 4; ++n) {
            coln[n] = col0 + p * BN + wc * 64 + n * 16 + lr;
            biasv[n] = bias[coln[n]];
            if (FUSEA) { wlv[n] = wl[coln[n]]; wrv[n] = wr[coln[n]]; }
        }
        int head = (col0 + p * BN + wc * 64) >> 6;
#pragma unroll
        for (int m = 0; m < MREP; ++m) {
#pragma unroll
            for (int e = 0; e < 4; ++e) {
                int row = m0 + wr_ * MROWS + m * 16 + lg * 4 + e;
                bool ok = row < Nn;
                float vv[4], p1 = 0.f, p2 = 0.f;
#pragma unroll
                for (int n = 0; n < 4; ++n) {
                    float v = acc[p][m][n][e] + biasv[n];
                    if (ADD) v += ok ? addp[(size_t)row * 64 + coln[n]] : 0.f;
                    if (FUSEA) { p1 += v * wlv[n]; p2 += v * wrv[n]; }
                    if (ELU) v = v > 0.f ? v : __expf(v) - 1.f;
                    vv[n] = v;
                }
                if (FUSEA) {
#pragma unroll
                    for (int o = 1; o < 16; o <<= 1) {
                        p1 += __shfl_xor(p1, o);
                        p2 += __shfl_xor(p2, o);
                    }
                    if (lr == 0 && ok) {
                        a1[(size_t)row * astride + head] = p1 + blp[head];
                        a2[(size_t)row * astride + head] = p2 + brp[head];
                    }
                }
                if (ok) {
#pragma unroll
                    for (int n = 0; n < 4; ++n) {
                        if (BF16OUT)
                            outb[(size_t)row * ostride + coln[n]] = f2bf(vv[n]);
                        else
                            outf[(size_t)row * ostride + coln[n]] = vv[n];
                    }
                }
            }
        }
    }
}

// ---------------- max pass (CSC walk), 4 nodes/wave: 16 lanes = 4 slots x 4 heads ----------------
__global__ __launch_bounds__(256) void maxpass4_k(const int* __restrict__ rowpd,
                                                  const int* __restrict__ cscsrc,
                                                  const float* __restrict__ a1,
                                                  const float* __restrict__ a2,
                                                  float* __restrict__ mmax) {
    int tid = threadIdx.x;
    int node = blockIdx.x * 16 + (tid >> 4);
    if (node >= Nn) return;
    int l16 = tid & 15;
    int slot = l16 >> 2, h = l16 & 3;
    int r0 = rowpd[node], r1 = rowpd[node + 1];
    float a1v = a1[node * 4 + h];
    float m = 0.f;
    for (int i = r0 + slot; i < r1; i += 4) {
        int s = cscsrc[i];
        float v = a1v + a2[s * 4 + h];
        float a = v > 0.f ? v : 0.01f * v;
        m = fmaxf(m, a);
    }
    m = fmaxf(m, __shfl_xor(m, 4));
    m = fmaxf(m, __shfl_xor(m, 8));
    if (slot == 0) mmax[node * 4 + h] = m;
}

// ---------------- max pass layer2, 4 nodes/wave: 16 slots each ----------------
__global__ __launch_bounds__(256) void maxpass1_k(const int* __restrict__ rowpd,
                                                  const int* __restrict__ cscsrc,
                                                  const float* __restrict__ a1,
                                                  const float* __restrict__ a2,
                                                  float* __restrict__ mmax) {
    int tid = threadIdx.x;
    int node = blockIdx.x * 16 + (tid >> 4);
    if (node >= Nn) return;
    int slot = tid & 15;
    int r0 = rowpd[node], r1 = rowpd[node + 1];
    float a1v = a1[node];
    float m = 0.f;
    for (int i = r0 + slot; i < r1; i += 16) {
        float v = a1v + a2[cscsrc[i]];
        float a = v > 0.f ? v : 0.01f * v;
        m = fmaxf(m, a);
    }
#pragma unroll
    for (int o = 1; o < 16; o <<= 1) m = fmaxf(m, __shfl_xor(m, o));
    if (slot == 0) mmax[node] = m;
}

// ---------------- sum pass (CSR walk), 4 nodes/wave; packs P = {a1, m, 1/S} ----------------
__global__ __launch_bounds__(256) void sumpass4_k(const int* __restrict__ rowps,
                                                  const int* __restrict__ csrdst,
                                                  const float* __restrict__ a1,
                                                  const float* __restrict__ a2,
                                                  const float* __restrict__ mmax,
                                                  float4* __restrict__ P4) {
    int tid = threadIdx.x;
    int node = blockIdx.x * 16 + (tid >> 4);
    if (node >= Nn) return;
    int l16 = tid & 15;
    int slot = l16 >> 2, h = l16 & 3;
    int r0 = rowps[node], r1 = rowps[node + 1];
    float a2v = a2[node * 4 + h];
    float S = 0.f;
    for (int i = r0 + slot; i < r1; i += 4) {
        int d = csrdst[i];
        float v = a1[d * 4 + h] + a2v;
        float a = v > 0.f ? v : 0.01f * v;
        S += __expf(a - mmax[d * 4 + h]);
    }
    S += __shfl_xor(S, 4);
    S += __shfl_xor(S, 8);
    if (slot == 0)
        P4[node * 4 + h] = make_float4(a1[node * 4 + h], mmax[node * 4 + h], 1.0f / S, 0.f);
}

__global__ __launch_bounds__(256) void sumpass1_k(const int* __restrict__ rowps,
                                                  const int* __restrict__ csrdst,
                                                  const float* __restrict__ a1,
                                                  const float* __restrict__ a2,
                                                  const float* __restrict__ mmax,
                                                  float4* __restrict__ P2) {
    int tid = threadIdx.x;
    int node = blockIdx.x * 16 + (tid >> 4);
    if (node >= Nn) return;
    int slot = tid & 15;
    int r0 = rowps[node], r1 = rowps[node + 1];
    float a2v = a2[node];
    float S = 0.f;
    for (int i = r0 + slot; i < r1; i += 16) {
        int d = csrdst[i];
        float v = a1[d] + a2v;
        float a = v > 0.f ? v : 0.01f * v;
        S += __expf(a - mmax[d]);
    }
#pragma unroll
    for (int o = 1; o < 16; o <<= 1) S += __shfl_xor(S, o);
    if (slot == 0)
        P2[node] = make_float4(a1[node], mmax[node], 1.0f / S, 0.f);
}

// ---------------- edge pass C (layer 1, 4 heads), 4-edge batched, ea recomputed ----------------
__global__ __launch_bounds__(256) void edgeC4_k(const int* __restrict__ rowp,
                                                const int* __restrict__ cdst,
                                                const float4* __restrict__ P4,
                                                const float* __restrict__ a2,
                                                const ushort_t* __restrict__ ftb,
                                                ushort_t* __restrict__ lastb) {
    int node = blockIdx.x * 4 + (threadIdx.x >> 6);
    int lane = threadIdx.x & 63;
    if (node >= Nn) return;
    int h = lane >> 4;
    float a2v = a2[node * 4 + h];
    const ushort_t* ftl = ftb + lane * 4;
    int r0 = rowp[node], r1 = rowp[node + 1];
    float ax = 0.f, ay = 0.f, az = 0.f, aw = 0.f;
    int i = r0;
    for (; i + 4 <= r1; i += 4) {
        int d[4];
        uint2 f[4];
        float4 P[4];
        float w[4];
#pragma unroll
        for (int j = 0; j < 4; ++j) d[j] = cdst[i + j];
#pragma unroll
        for (int j = 0; j < 4; ++j) f[j] = *(const uint2*)(ftl + (size_t)d[j] * 256);
#pragma unroll
        for (int j = 0; j < 4; ++j) P[j] = P4[(size_t)d[j] * 4 + h];
#pragma unroll
        for (int j = 0; j < 4; ++j) {
            float v = P[j].x + a2v;
            v = v > 0.f ? v : 0.01f * v;
            w[j] = __expf(v - P[j].y) * P[j].z;
        }
#pragma unroll
        for (int j = 0; j < 4; ++j) {
            ax += w[j] * bflo(f[j].x);
            ay += w[j] * bfhi(f[j].x);
            az += w[j] * bflo(f[j].y);
            aw += w[j] * bfhi(f[j].y);
        }
    }
    for (; i < r1; ++i) {
        int d = cdst[i];
        uint2 f = *(const uint2*)(ftl + (size_t)d * 256);
        float4 P = P4[(size_t)d * 4 + h];
        float v = P.x + a2v;
        v = v > 0.f ? v : 0.01f * v;
        float w = __expf(v - P.y) * P.z;
        ax += w * bflo(f.x);
        ay += w * bfhi(f.x);
        az += w * bflo(f.y);
        aw += w * bfhi(f.y);
    }
    ax = ax > 0.f ? ax : __expf(ax) - 1.f;
    ay = ay > 0.f ? ay : __expf(ay) - 1.f;
    az = az > 0.f ? az : __expf(az) - 1.f;
    aw = aw > 0.f ? aw : __expf(aw) - 1.f;
    uint2 o2;
    o2.x = (unsigned)f2bf(ax) | ((unsigned)f2bf(ay) << 16);
    o2.y = (unsigned)f2bf(az) | ((unsigned)f2bf(aw) << 16);
    *(uint2*)(lastb + (size_t)node * 256 + lane * 4) = o2;
}

// ---------------- edge pass C (layer 2), 8-edge batched (4 per half-wave), ea recomputed ----------------
__global__ __launch_bounds__(256) void edgeC1_k(const int* __restrict__ rowp,
                                                const int* __restrict__ cdst,
                                                const float4* __restrict__ P2,
                                                const float* __restrict__ a2,
                                                const ushort_t* __restrict__ ftb2,
                                                float* __restrict__ outp) {
    int node = blockIdx.x * 4 + (threadIdx.x >> 6);
    int lane = threadIdx.x & 63;
    if (node >= Nn) return;
    int half = lane >> 5, l = lane & 31;
    float a2v = a2[node];
    const ushort_t* ftl = ftb2 + l * 2;
    int r0 = rowp[node], r1 = rowp[node + 1];
    float acc0 = 0.f, acc1 = 0.f;
    int i0 = r0;
    for (; i0 + 8 <= r1; i0 += 8) {
        int d[4];
        unsigned f[4];
        float4 P[4];
        float w[4];
#pragma unroll
        for (int j = 0; j < 4; ++j) d[j] = cdst[i0 + 2 * j + half];
#pragma unroll
        for (int j = 0; j < 4; ++j) f[j] = *(const unsigned*)(ftl + (size_t)d[j] * 64);
#pragma unroll
        for (int j = 0; j < 4; ++j) P[j] = P2[d[j]];
#pragma unroll
        for (int j = 0; j < 4; ++j) {
            float v = P[j].x + a2v;
            v = v > 0.f ? v : 0.01f * v;
            w[j] = __expf(v - P[j].y) * P[j].z;
        }
#pragma unroll
        for (int j = 0; j < 4; ++j) {
            acc0 += w[j] * bflo(f[j]);
            acc1 += w[j] * bfhi(f[j]);
        }
    }
    for (; i0 < r1; i0 += 2) {
        int i = i0 + half;
        if (i < r1) {
            int d = cdst[i];
            unsigned f = *(const unsigned*)(ftl + (size_t)d * 64);
            float4 P = P2[d];
            float v = P.x + a2v;
            v = v > 0.f ? v : 0.01f * v;
            float w = __expf(v - P.y) * P.z;
            acc0 += w * bflo(f);
            acc1 += w * bfhi(f);
        }
    }
    acc0 += __shfl_xor(acc0, 32);
    acc1 += __shfl_xor(acc1, 32);
    if (lane < 32) {
        *(float2*)(outp + (size_t)node * 64 + l * 2) = make_float2(acc0, acc1);
    }
}

// ---------------- launch ----------------
extern "C" void kernel_launch(void* const* d_in, const int* in_sizes, int n_in,
                              void* d_out, int out_size, void* d_ws, size_t ws_size,
                              hipStream_t stream) {
    const float* features = (const float*)d_in[0];
    const int* src = (const int*)d_in[1];
    const int* dst = (const int*)d_in[2];
    const float* W_fc = (const float*)d_in[3];
    const float* b_fc = (const float*)d_in[4];
    const float* w_al = (const float*)d_in[5];
    const float* b_al = (const float*)d_in[6];
    const float* w_ar = (const float*)d_in[7];
    const float* b_ar = (const float*)d_in[8];
    const float* W_res = (const float*)d_in[9];
    const float* b_res = (const float*)d_in[10];
    float* out = (float*)d_out;
    char* ws = (char*)d_ws;

    int* rowps = (int*)(ws + O_ROWPS);
    int* rowpd = (int*)(ws + O_ROWPD);
    int* boff = (int*)(ws + O_BOFF);
    int* gcur = (int*)(ws + O_GCUR);
    int* csr_dst = (int*)(ws + O_CSRDST);
    int* csc_src = (int*)(ws + O_CSCSRC);
    int2* bufs = (int2*)(ws + O_BUFS);
    int2* bufd = (int2*)(ws + O_BUFD);
    ushort_t* ftb1 = (ushort_t*)(ws + O_FTB1);
    ushort_t* ftb2 = (ushort_t*)(ws + O_FTB2);
    ushort_t* lastb = (ushort_t*)(ws + O_LASTB);
    float4* P4 = (float4*)(ws + O_P4);
    float4* P2 = (float4*)(ws + O_P2);
    float* m4 = (float*)(ws + O_M4);
    float* a1_4 = (float*)(ws + O_A14);
    float* a2_4 = (float*)(ws + O_A24);
    float* m2 = (float*)(ws + O_M2);
    float* a1_2 = (float*)(ws + O_A12);
    float* a2_2 = (float*)(ws + O_A22);
    float* out2 = (float*)(ws + O_OUT2);
    ushort_t* Wt1 = (ushort_t*)(ws + O_WT1);
    ushort_t* Wt2 = (ushort_t*)(ws + O_WT2);
    ushort_t* WtR = (ushort_t*)(ws + O_WTR);

    // ---- weight convert/transpose (tiny) ----
    wcvt_k<<<384, 256, 0, stream>>>(W_fc, W_res, Wt1, Wt2, WtR);

    // ---- graph build: bucketed counting sort ----
    hipMemsetAsync(gcur, 0, 2 * NBUCK * 4, stream);
    p3_bin_k<<<NBLK3, 256, 0, stream>>>(src, dst, gcur, bufs, bufd);
    p2_scan_k<<<2, 512, 0, stream>>>(gcur, boff, rowps, rowpd);
    p4_fill_k<<<dim3(NBUCK, 2), 256, 0, stream>>>(gcur, boff, bufs, bufd,
                                                  rowps, rowpd, csr_dst, csc_src);

    const int GB = (Nn + 127) / 128;   // 782
    const int NW = (Nn + 3) / 4;       // 25000
    const int NW16 = (Nn + 15) / 16;   // 6250
    // ---- layer 1: single-dispatch MFMA GEMM, all 4 heads, features read once ----
    mgemm_k<0, 128, 2, 2, 1, 0, 0, 1><<<dim3(GB, 1), 256, 0, stream>>>(
        features, nullptr, Wt1, b_fc, nullptr,
        ftb1, nullptr, 256, w_al, w_ar, b_al, b_ar, a1_4, a2_4, 4);
    maxpass4_k<<<NW16, 256, 0, stream>>>(rowpd, csc_src, a1_4, a2_4, m4);
    sumpass4_k<<<NW16, 256, 0, stream>>>(rowps, csr_dst, a1_4, a2_4, m4, P4);
    edgeC4_k<<<NW, 256, 0, stream>>>(rowps, csr_dst, P4, a2_4, ftb1, lastb);

    // ---- layer 2: head 4 (A = lastb bf16) ----
    mgemm_k<1, 64, 1, 4, 1, 0, 0, 1><<<dim3(GB, 1), 256, 0, stream>>>(
        nullptr, lastb, Wt2, b_fc + 256, nullptr,
        ftb2, nullptr, 64, w_al + 256, w_ar + 256, b_al + 4, b_ar + 4,
        a1_2, a2_2, 1);
    maxpass1_k<<<NW16, 256, 0, stream>>>(rowpd, csc_src, a1_2, a2_2, m2);
    sumpass1_k<<<NW16, 256, 0, stream>>>(rowps, csr_dst, a1_2, a2_2, m2, P2);
    edgeC1_k<<<NW, 256, 0, stream>>>(rowps, csr_dst, P2, a2_2, ftb2, out2);

    // ---- final: elu(lastb @ WtR^T + b_res + out2) -> f32 out ----
    mgemm_k<1, 64, 1, 4, 0, 1, 1, 0><<<dim3(GB, 1), 256, 0, stream>>>(
        nullptr, lastb, WtR, b_res, out2,
        nullptr, out, 64, nullptr, nullptr, nullptr, nullptr, nullptr, nullptr, 0);
}

// Round 14
// 480.977 us; speedup vs baseline: 1.0124x; 1.0124x over previous
//
#include <hip/hip_runtime.h>

typedef unsigned short ushort_t;
typedef __attribute__((ext_vector_type(8))) short bf16x8;
typedef __attribute__((ext_vector_type(4))) float f32x4;

// ---------------- problem constants ----------------
constexpr int Nn = 100000;   // nodes
constexpr int Ee = 1600000;  // edges
// IN = 256, H = 64, NH = 4 (layer1 heads), head 4 = output head

constexpr int NBUCK = 391;   // ceil(Nn/256) node buckets of 256
constexpr int BCAP  = 6144;  // per-bucket capacity (mean 4096, sigma ~64)
constexpr int CH3   = 8192;  // edges per block in bin pass
constexpr int NBLK3 = (Ee + CH3 - 1) / CH3;  // 196

// ---------------- workspace layout (bytes) ----------------
constexpr size_t O_ROWPS  = 0;              // (Nn+1) int
constexpr size_t O_ROWPD  = 400512;         // (Nn+1) int
constexpr size_t O_BOFF   = 801024;         // 2*392 int
constexpr size_t O_GCUR   = 805120;         // 2*391 int
constexpr size_t O_CSRDST = 809216;         // Ee int
constexpr size_t O_CSCSRC = 7209216;        // Ee int
constexpr size_t O_FTB1   = 13609216;       // Nn*256 bf16 (51.2MB)
constexpr size_t O_FTB2   = 64809216;       // Nn*64 bf16
constexpr size_t O_LASTB  = 77609216;       // Nn*256 bf16 (51.2MB)
constexpr size_t O_EACSR  = 180009216;      // Ee*4 f32 (layer1) / Ee f32 (layer2)
constexpr size_t O_M4     = 205609216;      // Nn*4 f32
constexpr size_t O_S4     = 207209216;      // Nn*4 f32 (stores 1/S)
constexpr size_t O_A14    = 208809216;      // Nn*4 f32
constexpr size_t O_A24    = 210409216;      // Nn*4 f32
constexpr size_t O_M2     = 212009216;      // Nn f32
constexpr size_t O_S2     = 212409728;      // Nn f32 (stores 1/S)
constexpr size_t O_A12    = 212810240;      // Nn f32
constexpr size_t O_A22    = 213210752;      // Nn f32
constexpr size_t O_OUT2   = 213611264;      // Nn*64 f32
constexpr size_t O_WT1    = 239211264;      // 256*256 bf16 (layer1 weights, [col][k])
constexpr size_t O_WT2    = 239342336;      // 64*256 bf16
constexpr size_t O_WTR    = 239375104;      // 64*256 bf16   end ~239.4MB
// aliases (lifetimes disjoint):
constexpr size_t O_BUFS   = O_FTB1;
constexpr size_t O_BUFD   = O_FTB1 + (size_t)NBUCK * BCAP * 8;
constexpr size_t O_EAL2   = O_EACSR;

__device__ __forceinline__ ushort_t f2bf(float x) {
    unsigned u = __float_as_uint(x);
    unsigned r = (u + 0x7FFFu + ((u >> 16) & 1u)) >> 16;
    return (ushort_t)r;
}
__device__ __forceinline__ float bflo(unsigned u) { return __uint_as_float(u << 16); }
__device__ __forceinline__ float bfhi(unsigned u) { return __uint_as_float(u & 0xffff0000u); }

// ---------------- weight pre-transpose+convert: Wt[col][k] bf16 ----------------
__global__ void wcvt_k(const float* __restrict__ Wfc, const float* __restrict__ Wres,
                       ushort_t* __restrict__ Wt1, ushort_t* __restrict__ Wt2,
                       ushort_t* __restrict__ WtR) {
    int g = blockIdx.x * 256 + threadIdx.x;
    if (g < 65536) {
        int c = g >> 8, k = g & 255;
        Wt1[g] = f2bf(Wfc[(size_t)(c >> 6) * 16384 + k * 64 + (c & 63)]);
    } else if (g < 81920) {
        int q = g - 65536;
        int c = q >> 8, k = q & 255;
        Wt2[q] = f2bf(Wfc[4 * 16384 + k * 64 + c]);
    } else {
        int q = g - 81920;
        int c = q >> 8, k = q & 255;
        WtR[q] = f2bf(Wres[k * 64 + c]);
    }
}

// ---------------- P3: bin edges into node-range buckets (both orderings) ----------------
__global__ __launch_bounds__(256) void p3_bin_k(const int* __restrict__ src,
                                                const int* __restrict__ dst,
                                                int* __restrict__ gcur,
                                                int2* __restrict__ bufs,
                                                int2* __restrict__ bufd) {
    __shared__ int hs[NBUCK], hd[NBUCK], rs[NBUCK], rd[NBUCK];
    int t = threadIdx.x;
    for (int i = t; i < NBUCK; i += 256) { hs[i] = 0; hd[i] = 0; }
    __syncthreads();
    int e0 = blockIdx.x * CH3;
    int ne = min(CH3, Ee - e0);
    for (int i = t; i < ne; i += 256) {
        atomicAdd(&hs[src[e0 + i] >> 8], 1);
        atomicAdd(&hd[dst[e0 + i] >> 8], 1);
    }
    __syncthreads();
    for (int i = t; i < NBUCK; i += 256) {
        rs[i] = hs[i] ? atomicAdd(&gcur[i], hs[i]) : 0;
        rd[i] = hd[i] ? atomicAdd(&gcur[NBUCK + i], hd[i]) : 0;
        hs[i] = 0; hd[i] = 0;
    }
    __syncthreads();
    for (int i = t; i < ne; i += 256) {
        int s = src[e0 + i], d = dst[e0 + i];
        int bu = s >> 8;
        int pos = rs[bu] + atomicAdd(&hs[bu], 1);
        if (pos < BCAP) bufs[(size_t)bu * BCAP + pos] = make_int2(s, d);
        bu = d >> 8;
        pos = rd[bu] + atomicAdd(&hd[bu], 1);
        if (pos < BCAP) bufd[(size_t)bu * BCAP + pos] = make_int2(d, s);
    }
}

// ---------------- P2: scan bucket counts ----------------
__global__ void p2_scan_k(const int* __restrict__ gcur, int* __restrict__ boff,
                          int* __restrict__ rowps, int* __restrict__ rowpd) {
    __shared__ int sh[512];
    int t = threadIdx.x;
    const int* cnt = gcur + blockIdx.x * NBUCK;
    int* bo = boff + blockIdx.x * 392;
    int v = (t < NBUCK) ? min(cnt[t], BCAP) : 0;
    sh[t] = v;
    __syncthreads();
    for (int o = 1; o < 512; o <<= 1) {
        int x = (t >= o) ? sh[t - o] : 0;
        __syncthreads();
        sh[t] += x;
        __syncthreads();
    }
    if (t < NBUCK) bo[t] = sh[t] - v;
    if (t == NBUCK - 1) {
        bo[NBUCK] = sh[t];
        int* rp = blockIdx.x ? rowpd : rowps;
        rp[Nn] = sh[t];
    }
}

// ---------------- P4: per-bucket fill ----------------
__global__ __launch_bounds__(256) void p4_fill_k(const int* __restrict__ gcur,
                                                 const int* __restrict__ boff,
                                                 const int2* __restrict__ bufs,
                                                 const int2* __restrict__ bufd,
                                                 int* __restrict__ rowps,
                                                 int* __restrict__ rowpd,
                                                 int* __restrict__ csr_dst,
                                                 int* __restrict__ csc_src) {
    __shared__ int cnt[256], lofs[256], sc[256];
    int b = blockIdx.x, st = blockIdx.y;
    const int2* buf = (st ? bufd : bufs) + (size_t)b * BCAP;
    int base = boff[st * 392 + b];
    int total = min(gcur[st * NBUCK + b], BCAP);
    int* rowp = st ? rowpd : rowps;
    int* outv = st ? csc_src : csr_dst;
    int t = threadIdx.x, node0 = b << 8;
    cnt[t] = 0;
    __syncthreads();
    for (int i = t; i < total; i += 256) atomicAdd(&cnt[buf[i].x - node0], 1);
    __syncthreads();
    int v = cnt[t];
    sc[t] = v;
    __syncthreads();
    for (int o = 1; o < 256; o <<= 1) {
        int x = (t >= o) ? sc[t - o] : 0;
        __syncthreads();
        sc[t] += x;
        __syncthreads();
    }
    lofs[t] = sc[t] - v;
    if (node0 + t < Nn) rowp[node0 + t] = base + lofs[t];
    cnt[t] = 0;
    __syncthreads();
    for (int i = t; i < total; i += 256) {
        int2 p = buf[i];
        int k = p.x - node0;
        int r = atomicAdd(&cnt[k], 1);
        outv[base + lofs[k] + r] = p.y;
    }
}

// ---------------- MFMA GEMM: C[N, NPAN*BN] = A[N,256] @ Bt^T + bias (+add) ----------------
template <int ABF16, int BN, int NPAN, int WGM, int FUSEA, int ADD, int ELU, int BF16OUT>
__global__ __launch_bounds__(256) void mgemm_k(
    const float* __restrict__ Af, const ushort_t* __restrict__ Ab,
    const ushort_t* __restrict__ Bt, const float* __restrict__ bias,
    const float* __restrict__ addp,
    ushort_t* __restrict__ outb, float* __restrict__ outf, int ostride,
    const float* __restrict__ wl, const float* __restrict__ wr,
    const float* __restrict__ blp, const float* __restrict__ brp,
    float* __restrict__ a1, float* __restrict__ a2, int astride) {
    constexpr int MROWS = 128 / WGM;
    constexpr int MREP = MROWS / 16;
    constexpr int LDA = 40;  // shorts per LDS row (32 + 8 pad -> 2-way conflicts only)
    __shared__ short As[128 * LDA];
    __shared__ short Bs[NPAN][BN * LDA];
    int tid = threadIdx.x;
    int m0 = blockIdx.x * 128;
    int col0 = blockIdx.y * (BN * NPAN);
    int w = tid >> 6, l = tid & 63;
    int wr_ = w % WGM, wc = w / WGM;
    int lr = l & 15, lg = l >> 4;
    f32x4 acc[NPAN][MREP][4];
#pragma unroll
    for (int p = 0; p < NPAN; ++p)
#pragma unroll
        for (int m = 0; m < MREP; ++m)
#pragma unroll
            for (int n = 0; n < 4; ++n) acc[p][m][n] = (f32x4){0.f, 0.f, 0.f, 0.f};

    for (int kc = 0; kc < 8; ++kc) {
        int k0 = kc * 32;
        if (ABF16 == 0) {
            int r = tid >> 1, half = tid & 1;
            int grow = m0 + r;
            float4 f0, f1, f2, f3;
            if (grow < Nn) {
                const float4* ap = (const float4*)(Af + (size_t)grow * 256 + k0 + half * 16);
                f0 = ap[0]; f1 = ap[1]; f2 = ap[2]; f3 = ap[3];
            } else {
                f0 = f1 = f2 = f3 = make_float4(0.f, 0.f, 0.f, 0.f);
            }
            bf16x8 s0, s1;
            s0[0] = f2bf(f0.x); s0[1] = f2bf(f0.y); s0[2] = f2bf(f0.z); s0[3] = f2bf(f0.w);
            s0[4] = f2bf(f1.x); s0[5] = f2bf(f1.y); s0[6] = f2bf(f1.z); s0[7] = f2bf(f1.w);
            s1[0] = f2bf(f2.x); s1[1] = f2bf(f2.y); s1[2] = f2bf(f2.z); s1[3] = f2bf(f2.w);
            s1[4] = f2bf(f3.x); s1[5] = f2bf(f3.y); s1[6] = f2bf(f3.z); s1[7] = f2bf(f3.w);
            *(bf16x8*)&As[r * LDA + half * 16] = s0;
            *(bf16x8*)&As[r * LDA + half * 16 + 8] = s1;
        } else {
#pragma unroll
            for (int i = 0; i < 2; ++i) {
                int s = tid + i * 256, r = s >> 2, q = s & 3;
                int grow = m0 + r;
                int4 v = make_int4(0, 0, 0, 0);
                if (grow < Nn) v = *(const int4*)(Ab + (size_t)grow * 256 + k0 + q * 8);
                *(int4*)&As[r * LDA + q * 8] = v;
            }
        }
#pragma unroll
        for (int p = 0; p < NPAN; ++p)
#pragma unroll
            for (int i = 0; i < BN / 64; ++i) {
                int s = tid + i * 256, c = s >> 2, q = s & 3;
                int4 v = *(const int4*)(Bt + (size_t)(col0 + p * BN + c) * 256 + k0 + q * 8);
                *(int4*)&Bs[p][c * LDA + q * 8] = v;
            }
        __syncthreads();
        bf16x8 af[MREP];
#pragma unroll
        for (int m = 0; m < MREP; ++m)
            af[m] = *(const bf16x8*)&As[(wr_ * MROWS + m * 16 + lr) * LDA + lg * 8];
#pragma unroll
        for (int p = 0; p < NPAN; ++p) {
            bf16x8 bfr[4];
#pragma unroll
            for (int n = 0; n < 4; ++n)
                bfr[n] = *(const bf16x8*)&Bs[p][(wc * 64 + n * 16 + lr) * LDA + lg * 8];
#pragma unroll
            for (int m = 0; m < MREP; ++m)
#pragma unroll
                for (int n = 0; n < 4; ++n)
                    acc[p][m][n] = __builtin_amdgcn_mfma_f32_16x16x32_bf16(af[m], bfr[n], acc[p][m][n], 0, 0, 0);
        }
        __syncthreads();
    }

#pragma unroll
    for (int p = 0; p < NPAN; ++p) {
        int coln[4];
        float biasv[4], wlv[4] = {}, wrv[4] = {};
#pragma unroll
        for (int n = 0; n < 4; ++n) {
            coln[n] = col0 + p * BN + wc * 64 + n * 16 + lr;
            biasv[n] = bias[coln[n]];
            if (FUSEA) { wlv[n] = wl[coln[n]]; wrv[n] = wr[coln[n]]; }
        }
        int head = (col0 + p * BN + wc * 64) >> 6;
#pragma unroll
        for (int m = 0; m < MREP; ++m) {
#pragma unroll
            for (int e = 0; e < 4; ++e) {
                int row = m0 + wr_ * MROWS + m * 16 + lg * 4 + e;
                bool ok = row < Nn;
                float vv[4], p1 = 0.f, p2 = 0.f;
#pragma unroll
                for (int n = 0; n < 4; ++n) {
                    float v = acc[p][m][n][e] + biasv[n];
                    if (ADD) v += ok ? addp[(size_t)row * 64 + coln[n]] : 0.f;
                    if (FUSEA) { p1 += v * wlv[n]; p2 += v * wrv[n]; }
                    if (ELU) v = v > 0.f ? v : __expf(v) - 1.f;
                    vv[n] = v;
                }
                if (FUSEA) {
#pragma unroll
                    for (int o = 1; o < 16; o <<= 1) {
                        p1 += __shfl_xor(p1, o);
                        p2 += __shfl_xor(p2, o);
                    }
                    if (lr == 0 && ok) {
                        a1[(size_t)row * astride + head] = p1 + blp[head];
                        a2[(size_t)row * astride + head] = p2 + brp[head];
                    }
                }
                if (ok) {
#pragma unroll
                    for (int n = 0; n < 4; ++n) {
                        if (BF16OUT)
                            outb[(size_t)row * ostride + coln[n]] = f2bf(vv[n]);
                        else
                            outf[(size_t)row * ostride + coln[n]] = vv[n];
                    }
                }
            }
        }
    }
}

// ---------------- max pass (CSC walk), 4 nodes/wave: 16 lanes = 4 slots x 4 heads ----------------
__global__ __launch_bounds__(256) void maxpass4_k(const int* __restrict__ rowpd,
                                                  const int* __restrict__ cscsrc,
                                                  const float* __restrict__ a1,
                                                  const float* __restrict__ a2,
                                                  float* __restrict__ mmax) {
    int tid = threadIdx.x;
    int node = blockIdx.x * 16 + (tid >> 4);
    if (node >= Nn) return;
    int l16 = tid & 15;
    int slot = l16 >> 2, h = l16 & 3;
    int r0 = rowpd[node], r1 = rowpd[node + 1];
    float a1v = a1[node * 4 + h];
    float m = 0.f;
    for (int i = r0 + slot; i < r1; i += 4) {
        int s = cscsrc[i];
        float v = a1v + a2[s * 4 + h];
        float a = v > 0.f ? v : 0.01f * v;
        m = fmaxf(m, a);
    }
    m = fmaxf(m, __shfl_xor(m, 4));
    m = fmaxf(m, __shfl_xor(m, 8));
    if (slot == 0) mmax[node * 4 + h] = m;
}

// ---------------- max pass layer2, 4 nodes/wave: 16 slots each ----------------
__global__ __launch_bounds__(256) void maxpass1_k(const int* __restrict__ rowpd,
                                                  const int* __restrict__ cscsrc,
                                                  const float* __restrict__ a1,
                                                  const float* __restrict__ a2,
                                                  float* __restrict__ mmax) {
    int tid = threadIdx.x;
    int node = blockIdx.x * 16 + (tid >> 4);
    if (node >= Nn) return;
    int slot = tid & 15;
    int r0 = rowpd[node], r1 = rowpd[node + 1];
    float a1v = a1[node];
    float m = 0.f;
    for (int i = r0 + slot; i < r1; i += 16) {
        float v = a1v + a2[cscsrc[i]];
        float a = v > 0.f ? v : 0.01f * v;
        m = fmaxf(m, a);
    }
#pragma unroll
    for (int o = 1; o < 16; o <<= 1) m = fmaxf(m, __shfl_xor(m, o));
    if (slot == 0) mmax[node] = m;
}

// ---------------- sum pass (CSR walk), 4 nodes/wave; stores 1/S ----------------
__global__ __launch_bounds__(256) void sumpass4_k(const int* __restrict__ rowps,
                                                  const int* __restrict__ csrdst,
                                                  const float* __restrict__ a1,
                                                  const float* __restrict__ a2,
                                                  const float* __restrict__ mmax,
                                                  float* __restrict__ eacsr,
                                                  float* __restrict__ Sinv) {
    int tid = threadIdx.x;
    int node = blockIdx.x * 16 + (tid >> 4);
    if (node >= Nn) return;
    int l16 = tid & 15;
    int slot = l16 >> 2, h = l16 & 3;
    int r0 = rowps[node], r1 = rowps[node + 1];
    float a2v = a2[node * 4 + h];
    float S = 0.f;
    for (int i = r0 + slot; i < r1; i += 4) {
        int d = csrdst[i];
        float v = a1[d * 4 + h] + a2v;
        float a = v > 0.f ? v : 0.01f * v;
        float ea = __expf(a - mmax[d * 4 + h]);
        eacsr[(size_t)i * 4 + h] = ea;
        S += ea;
    }
    S += __shfl_xor(S, 4);
    S += __shfl_xor(S, 8);
    if (slot == 0) Sinv[node * 4 + h] = 1.0f / S;
}

__global__ __launch_bounds__(256) void sumpass1_k(const int* __restrict__ rowps,
                                                  const int* __restrict__ csrdst,
                                                  const float* __restrict__ a1,
                                                  const float* __restrict__ a2,
                                                  const float* __restrict__ mmax,
                                                  float* __restrict__ eacsr,
                                                  float* __restrict__ Sinv) {
    int tid = threadIdx.x;
    int node = blockIdx.x * 16 + (tid >> 4);
    if (node >= Nn) return;
    int slot = tid & 15;
    int r0 = rowps[node], r1 = rowps[node + 1];
    float a2v = a2[node];
    float S = 0.f;
    for (int i = r0 + slot; i < r1; i += 16) {
        int d = csrdst[i];
        float v = a1[d] + a2v;
        float a = v > 0.f ? v : 0.01f * v;
        float ea = __expf(a - mmax[d]);
        eacsr[i] = ea;
        S += ea;
    }
#pragma unroll
    for (int o = 1; o < 16; o <<= 1) S += __shfl_xor(S, o);
    if (slot == 0) Sinv[node] = 1.0f / S;
}

// ---------------- edge pass C (layer 1, 4 heads), 4-edge batched ----------------
__global__ __launch_bounds__(256) void edgeC4_k(const int* __restrict__ rowp,
                                                const int* __restrict__ cdst,
                                                const float* __restrict__ eacsr,
                                                const float* __restrict__ Sinv4,
                                                const ushort_t* __restrict__ ftb,
                                                ushort_t* __restrict__ lastb) {
    int node = blockIdx.x * 4 + (threadIdx.x >> 6);
    int lane = threadIdx.x & 63;
    if (node >= Nn) return;
    int h = lane >> 4;
    const ushort_t* ftl = ftb + lane * 4;
    int r0 = rowp[node], r1 = rowp[node + 1];
    float ax = 0.f, ay = 0.f, az = 0.f, aw = 0.f;
    int i = r0;
    for (; i + 4 <= r1; i += 4) {
        int d[4];
        float w[4];
        uint2 f[4];
#pragma unroll
        for (int j = 0; j < 4; ++j) d[j] = cdst[i + j];
#pragma unroll
        for (int j = 0; j < 4; ++j) w[j] = eacsr[(size_t)(i + j) * 4 + h];
#pragma unroll
        for (int j = 0; j < 4; ++j) f[j] = *(const uint2*)(ftl + (size_t)d[j] * 256);
#pragma unroll
        for (int j = 0; j < 4; ++j) w[j] *= Sinv4[d[j] * 4 + h];
#pragma unroll
        for (int j = 0; j < 4; ++j) {
            ax += w[j] * bflo(f[j].x);
            ay += w[j] * bfhi(f[j].x);
            az += w[j] * bflo(f[j].y);
            aw += w[j] * bfhi(f[j].y);
        }
    }
    for (; i < r1; ++i) {
        int d = cdst[i];
        float w = eacsr[(size_t)i * 4 + h] * Sinv4[d * 4 + h];
        uint2 f = *(const uint2*)(ftl + (size_t)d * 256);
        ax += w * bflo(f.x);
        ay += w * bfhi(f.x);
        az += w * bflo(f.y);
        aw += w * bfhi(f.y);
    }
    ax = ax > 0.f ? ax : __expf(ax) - 1.f;
    ay = ay > 0.f ? ay : __expf(ay) - 1.f;
    az = az > 0.f ? az : __expf(az) - 1.f;
    aw = aw > 0.f ? aw : __expf(aw) - 1.f;
    uint2 o2;
    o2.x = (unsigned)f2bf(ax) | ((unsigned)f2bf(ay) << 16);
    o2.y = (unsigned)f2bf(az) | ((unsigned)f2bf(aw) << 16);
    *(uint2*)(lastb + (size_t)node * 256 + lane * 4) = o2;
}

// ---------------- edge pass C (layer 2), 8-edge batched (4 per half-wave) ----------------
__global__ __launch_bounds__(256) void edgeC1_k(const int* __restrict__ rowp,
                                                const int* __restrict__ cdst,
                                                const float* __restrict__ ea,
                                                const float* __restrict__ Sinv2,
                                                const ushort_t* __restrict__ ftb2,
                                                float* __restrict__ outp) {
    int node = blockIdx.x * 4 + (threadIdx.x >> 6);
    int lane = threadIdx.x & 63;
    if (node >= Nn) return;
    int half = lane >> 5, l = lane & 31;
    const ushort_t* ftl = ftb2 + l * 2;
    int r0 = rowp[node], r1 = rowp[node + 1];
    float acc0 = 0.f, acc1 = 0.f;
    int i0 = r0;
    for (; i0 + 8 <= r1; i0 += 8) {
        int d[4];
        float w[4];
        unsigned f[4];
#pragma unroll
        for (int j = 0; j < 4; ++j) {
            int idx = i0 + 2 * j + half;
            d[j] = cdst[idx];
            w[j] = ea[idx];
        }
#pragma unroll
        for (int j = 0; j < 4; ++j) f[j] = *(const unsigned*)(ftl + (size_t)d[j] * 64);
#pragma unroll
        for (int j = 0; j < 4; ++j) w[j] *= Sinv2[d[j]];
#pragma unroll
        for (int j = 0; j < 4; ++j) {
            acc0 += w[j] * bflo(f[j]);
            acc1 += w[j] * bfhi(f[j]);
        }
    }
    for (; i0 < r1; i0 += 2) {
        int i = i0 + half;
        if (i < r1) {
            int d = cdst[i];
            float w = ea[i] * Sinv2[d];
            unsigned f = *(const unsigned*)(ftl + (size_t)d * 64);
            acc0 += w * bflo(f);
            acc1 += w * bfhi(f);
        }
    }
    acc0 += __shfl_xor(acc0, 32);
    acc1 += __shfl_xor(acc1, 32);
    if (lane < 32) {
        *(float2*)(outp + (size_t)node * 64 + l * 2) = make_float2(acc0, acc1);
    }
}

// ---------------- launch ----------------
extern "C" void kernel_launch(void* const* d_in, const int* in_sizes, int n_in,
                              void* d_out, int out_size, void* d_ws, size_t ws_size,
                              hipStream_t stream) {
    const float* features = (const float*)d_in[0];
    const int* src = (const int*)d_in[1];
    const int* dst = (const int*)d_in[2];
    const float* W_fc = (const float*)d_in[3];
    const float* b_fc = (const float*)d_in[4];
    const float* w_al = (const float*)d_in[5];
    const float* b_al = (const float*)d_in[6];
    const float* w_ar = (const float*)d_in[7];
    const float* b_ar = (const float*)d_in[8];
    const float* W_res = (const float*)d_in[9];
    const float* b_res = (const float*)d_in[10];
    float* out = (float*)d_out;
    char* ws = (char*)d_ws;

    int* rowps = (int*)(ws + O_ROWPS);
    int* rowpd = (int*)(ws + O_ROWPD);
    int* boff = (int*)(ws + O_BOFF);
    int* gcur = (int*)(ws + O_GCUR);
    int* csr_dst = (int*)(ws + O_CSRDST);
    int* csc_src = (int*)(ws + O_CSCSRC);
    int2* bufs = (int2*)(ws + O_BUFS);
    int2* bufd = (int2*)(ws + O_BUFD);
    ushort_t* ftb1 = (ushort_t*)(ws + O_FTB1);
    ushort_t* ftb2 = (ushort_t*)(ws + O_FTB2);
    ushort_t* lastb = (ushort_t*)(ws + O_LASTB);
    float* eacsr = (float*)(ws + O_EACSR);
    float* m4 = (float*)(ws + O_M4);
    float* S4 = (float*)(ws + O_S4);
    float* a1_4 = (float*)(ws + O_A14);
    float* a2_4 = (float*)(ws + O_A24);
    float* m2 = (float*)(ws + O_M2);
    float* S2 = (float*)(ws + O_S2);
    float* a1_2 = (float*)(ws + O_A12);
    float* a2_2 = (float*)(ws + O_A22);
    float* out2 = (float*)(ws + O_OUT2);
    float* ea_l2 = (float*)(ws + O_EAL2);
    ushort_t* Wt1 = (ushort_t*)(ws + O_WT1);
    ushort_t* Wt2 = (ushort_t*)(ws + O_WT2);
    ushort_t* WtR = (ushort_t*)(ws + O_WTR);

    // ---- weight convert/transpose (tiny) ----
    wcvt_k<<<384, 256, 0, stream>>>(W_fc, W_res, Wt1, Wt2, WtR);

    // ---- graph build: bucketed counting sort ----
    hipMemsetAsync(gcur, 0, 2 * NBUCK * 4, stream);
    p3_bin_k<<<NBLK3, 256, 0, stream>>>(src, dst, gcur, bufs, bufd);
    p2_scan_k<<<2, 512, 0, stream>>>(gcur, boff, rowps, rowpd);
    p4_fill_k<<<dim3(NBUCK, 2), 256, 0, stream>>>(gcur, boff, bufs, bufd,
                                                  rowps, rowpd, csr_dst, csc_src);

    const int GB = (Nn + 127) / 128;   // 782
    const int NW = (Nn + 3) / 4;       // 25000
    const int NW16 = (Nn + 15) / 16;   // 6250
    // ---- layer 1: single-dispatch MFMA GEMM (NPAN=2, features read once) ----
    mgemm_k<0, 128, 2, 2, 1, 0, 0, 1><<<dim3(GB, 1), 256, 0, stream>>>(
        features, nullptr, Wt1, b_fc, nullptr,
        ftb1, nullptr, 256, w_al, w_ar, b_al, b_ar, a1_4, a2_4, 4);
    maxpass4_k<<<NW16, 256, 0, stream>>>(rowpd, csc_src, a1_4, a2_4, m4);
    sumpass4_k<<<NW16, 256, 0, stream>>>(rowps, csr_dst, a1_4, a2_4, m4, eacsr, S4);
    edgeC4_k<<<NW, 256, 0, stream>>>(rowps, csr_dst, eacsr, S4, ftb1, lastb);

    // ---- layer 2: head 4 (A = lastb bf16) ----
    mgemm_k<1, 64, 1, 4, 1, 0, 0, 1><<<dim3(GB, 1), 256, 0, stream>>>(
        nullptr, lastb, Wt2, b_fc + 256, nullptr,
        ftb2, nullptr, 64, w_al + 256, w_ar + 256, b_al + 4, b_ar + 4,
        a1_2, a2_2, 1);
    maxpass1_k<<<NW16, 256, 0, stream>>>(rowpd, csc_src, a1_2, a2_2, m2);
    sumpass1_k<<<NW16, 256, 0, stream>>>(rowps, csr_dst, a1_2, a2_2, m2, ea_l2, S2);
    edgeC1_k<<<NW, 256, 0, stream>>>(rowps, csr_dst, ea_l2, S2, ftb2, out2);

    // ---- final: elu(lastb @ WtR^T + b_res + out2) -> f32 out ----
    mgemm_k<1, 64, 1, 4, 0, 1, 1, 0><<<dim3(GB, 1), 256, 0, stream>>>(
        nullptr, lastb, WtR, b_res, out2,
        nullptr, out, 64, nullptr, nullptr, nullptr, nullptr, nullptr, nullptr, 0);
}

// Round 16
// 440.617 us; speedup vs baseline: 1.1051x; 1.0916x over previous
//
#include <hip/hip_runtime.h>

typedef unsigned short ushort_t;
typedef __attribute__((ext_vector_type(8))) short bf16x8;
typedef __attribute__((ext_vector_type(4))) float f32x4;

// ---------------- problem constants ----------------
constexpr int Nn = 100000;   // nodes
constexpr int Ee = 1600000;  // edges

constexpr int NBUCK = 391;
constexpr int BCAP  = 6144;
constexpr int CH3   = 8192;
constexpr int NBLK3 = (Ee + CH3 - 1) / CH3;  // 196

// ---------------- workspace layout (bytes) ----------------
constexpr size_t O_ROWPS  = 0;              // (Nn+1) int
constexpr size_t O_ROWPD  = 400512;         // (Nn+1) int
constexpr size_t O_BOFF   = 801024;         // 2*392 int
constexpr size_t O_GCUR   = 805120;         // 2*391 int
constexpr size_t O_CSRDST = 809216;         // Ee int
constexpr size_t O_CSCSRC = 7209216;        // Ee int
constexpr size_t O_FTB1   = 13609216;       // Nn*256 bf16 (51.2MB)
constexpr size_t O_FTB2   = 64809216;       // Nn*64 bf16
constexpr size_t O_LASTB  = 77609216;       // Nn*256 bf16 (51.2MB)
constexpr size_t O_EACSR  = 180009216;      // Ee*4 f32 (layer1) / Ee f32 (layer2 alias)
constexpr size_t O_PM4    = 205609216;      // Nn*4 float2 {a1,m} (3.2MB)
constexpr size_t O_S4     = 208809216;      // Nn*4 f32 (1/S)
constexpr size_t O_A14    = 210409216;      // Nn*4 f32
constexpr size_t O_A24    = 212009216;      // Nn*4 f32
constexpr size_t O_PM2    = 213609216;      // Nn float2 (800KB)
constexpr size_t O_S2     = 214409216;      // Nn f32 (1/S)
constexpr size_t O_A12    = 214809216;      // Nn f32
constexpr size_t O_A22    = 215209216;      // Nn f32
constexpr size_t O_OUT2   = 215609216;      // Nn*64 f32 (25.6MB)
constexpr size_t O_WT1    = 241209216;      // 256*256 bf16
constexpr size_t O_WT2    = 241340288;      // 64*256 bf16
constexpr size_t O_WTR    = 241373056;      // 64*256 bf16  end ~241.4MB
// aliases (lifetimes disjoint):
constexpr size_t O_BUFS   = O_FTB1;
constexpr size_t O_BUFD   = O_FTB1 + (size_t)NBUCK * BCAP * 8;
constexpr size_t O_EAL2   = O_EACSR;

__device__ __forceinline__ ushort_t f2bf(float x) {
    unsigned u = __float_as_uint(x);
    unsigned r = (u + 0x7FFFu + ((u >> 16) & 1u)) >> 16;
    return (ushort_t)r;
}
__device__ __forceinline__ float bflo(unsigned u) { return __uint_as_float(u << 16); }
__device__ __forceinline__ float bfhi(unsigned u) { return __uint_as_float(u & 0xffff0000u); }

// ---------------- weight pre-transpose+convert: Wt[col][k] bf16 ----------------
__global__ void wcvt_k(const float* __restrict__ Wfc, const float* __restrict__ Wres,
                       ushort_t* __restrict__ Wt1, ushort_t* __restrict__ Wt2,
                       ushort_t* __restrict__ WtR) {
    int g = blockIdx.x * 256 + threadIdx.x;
    if (g < 65536) {
        int c = g >> 8, k = g & 255;
        Wt1[g] = f2bf(Wfc[(size_t)(c >> 6) * 16384 + k * 64 + (c & 63)]);
    } else if (g < 81920) {
        int q = g - 65536;
        int c = q >> 8, k = q & 255;
        Wt2[q] = f2bf(Wfc[4 * 16384 + k * 64 + c]);
    } else {
        int q = g - 81920;
        int c = q >> 8, k = q & 255;
        WtR[q] = f2bf(Wres[k * 64 + c]);
    }
}

// ---------------- P3: bin edges into node-range buckets (both orderings) ----------------
__global__ __launch_bounds__(256) void p3_bin_k(const int* __restrict__ src,
                                                const int* __restrict__ dst,
                                                int* __restrict__ gcur,
                                                int2* __restrict__ bufs,
                                                int2* __restrict__ bufd) {
    __shared__ int hs[NBUCK], hd[NBUCK], rs[NBUCK], rd[NBUCK];
    int t = threadIdx.x;
    for (int i = t; i < NBUCK; i += 256) { hs[i] = 0; hd[i] = 0; }
    __syncthreads();
    int e0 = blockIdx.x * CH3;
    int ne = min(CH3, Ee - e0);
    for (int i = t; i < ne; i += 256) {
        atomicAdd(&hs[src[e0 + i] >> 8], 1);
        atomicAdd(&hd[dst[e0 + i] >> 8], 1);
    }
    __syncthreads();
    for (int i = t; i < NBUCK; i += 256) {
        rs[i] = hs[i] ? atomicAdd(&gcur[i], hs[i]) : 0;
        rd[i] = hd[i] ? atomicAdd(&gcur[NBUCK + i], hd[i]) : 0;
        hs[i] = 0; hd[i] = 0;
    }
    __syncthreads();
    for (int i = t; i < ne; i += 256) {
        int s = src[e0 + i], d = dst[e0 + i];
        int bu = s >> 8;
        int pos = rs[bu] + atomicAdd(&hs[bu], 1);
        if (pos < BCAP) bufs[(size_t)bu * BCAP + pos] = make_int2(s, d);
        bu = d >> 8;
        pos = rd[bu] + atomicAdd(&hd[bu], 1);
        if (pos < BCAP) bufd[(size_t)bu * BCAP + pos] = make_int2(d, s);
    }
}

// ---------------- P2: scan bucket counts ----------------
__global__ void p2_scan_k(const int* __restrict__ gcur, int* __restrict__ boff,
                          int* __restrict__ rowps, int* __restrict__ rowpd) {
    __shared__ int sh[512];
    int t = threadIdx.x;
    const int* cnt = gcur + blockIdx.x * NBUCK;
    int* bo = boff + blockIdx.x * 392;
    int v = (t < NBUCK) ? min(cnt[t], BCAP) : 0;
    sh[t] = v;
    __syncthreads();
    for (int o = 1; o < 512; o <<= 1) {
        int x = (t >= o) ? sh[t - o] : 0;
        __syncthreads();
        sh[t] += x;
        __syncthreads();
    }
    if (t < NBUCK) bo[t] = sh[t] - v;
    if (t == NBUCK - 1) {
        bo[NBUCK] = sh[t];
        int* rp = blockIdx.x ? rowpd : rowps;
        rp[Nn] = sh[t];
    }
}

// ---------------- P4: per-bucket fill ----------------
__global__ __launch_bounds__(256) void p4_fill_k(const int* __restrict__ gcur,
                                                 const int* __restrict__ boff,
                                                 const int2* __restrict__ bufs,
                                                 const int2* __restrict__ bufd,
                                                 int* __restrict__ rowps,
                                                 int* __restrict__ rowpd,
                                                 int* __restrict__ csr_dst,
                                                 int* __restrict__ csc_src) {
    __shared__ int cnt[256], lofs[256], sc[256];
    int b = blockIdx.x, st = blockIdx.y;
    const int2* buf = (st ? bufd : bufs) + (size_t)b * BCAP;
    int base = boff[st * 392 + b];
    int total = min(gcur[st * NBUCK + b], BCAP);
    int* rowp = st ? rowpd : rowps;
    int* outv = st ? csc_src : csr_dst;
    int t = threadIdx.x, node0 = b << 8;
    cnt[t] = 0;
    __syncthreads();
    for (int i = t; i < total; i += 256) atomicAdd(&cnt[buf[i].x - node0], 1);
    __syncthreads();
    int v = cnt[t];
    sc[t] = v;
    __syncthreads();
    for (int o = 1; o < 256; o <<= 1) {
        int x = (t >= o) ? sc[t - o] : 0;
        __syncthreads();
        sc[t] += x;
        __syncthreads();
    }
    lofs[t] = sc[t] - v;
    if (node0 + t < Nn) rowp[node0 + t] = base + lofs[t];
    cnt[t] = 0;
    __syncthreads();
    for (int i = t; i < total; i += 256) {
        int2 p = buf[i];
        int k = p.x - node0;
        int r = atomicAdd(&cnt[k], 1);
        outv[base + lofs[k] + r] = p.y;
    }
}

// ---------------- MFMA GEMM: C[N,BN] = A[N,256] @ Bt^T + bias (+add) ----------------
template <int ABF16, int BN, int WGM, int FUSEA, int ADD, int ELU, int BF16OUT>
__global__ __launch_bounds__(256) void mgemm_k(
    const float* __restrict__ Af, const ushort_t* __restrict__ Ab,
    const ushort_t* __restrict__ Bt, const float* __restrict__ bias,
    const float* __restrict__ addp,
    ushort_t* __restrict__ outb, float* __restrict__ outf, int ostride,
    const float* __restrict__ wl, const float* __restrict__ wr,
    const float* __restrict__ blp, const float* __restrict__ brp,
    float* __restrict__ a1, float* __restrict__ a2, int astride) {
    constexpr int MROWS = 128 / WGM;
    constexpr int MREP = MROWS / 16;
    constexpr int LDA = 40;  // shorts per LDS row (32 + 8 pad -> 2-way conflicts only)
    __shared__ short As[128 * LDA];
    __shared__ short Bs[BN * LDA];
    int tid = threadIdx.x;
    int m0 = blockIdx.x * 128;
    int col0 = blockIdx.y * BN;
    int w = tid >> 6, l = tid & 63;
    int wr_ = w % WGM, wc = w / WGM;
    int lr = l & 15, lg = l >> 4;
    f32x4 acc[MREP][4];
#pragma unroll
    for (int m = 0; m < MREP; ++m)
#pragma unroll
        for (int n = 0; n < 4; ++n) acc[m][n] = (f32x4){0.f, 0.f, 0.f, 0.f};

    for (int kc = 0; kc < 8; ++kc) {
        int k0 = kc * 32;
        if (ABF16 == 0) {
            int r = tid >> 1, half = tid & 1;
            int grow = m0 + r;
            float4 f0, f1, f2, f3;
            if (grow < Nn) {
                const float4* ap = (const float4*)(Af + (size_t)grow * 256 + k0 + half * 16);
                f0 = ap[0]; f1 = ap[1]; f2 = ap[2]; f3 = ap[3];
            } else {
                f0 = f1 = f2 = f3 = make_float4(0.f, 0.f, 0.f, 0.f);
            }
            bf16x8 s0, s1;
            s0[0] = f2bf(f0.x); s0[1] = f2bf(f0.y); s0[2] = f2bf(f0.z); s0[3] = f2bf(f0.w);
            s0[4] = f2bf(f1.x); s0[5] = f2bf(f1.y); s0[6] = f2bf(f1.z); s0[7] = f2bf(f1.w);
            s1[0] = f2bf(f2.x); s1[1] = f2bf(f2.y); s1[2] = f2bf(f2.z); s1[3] = f2bf(f2.w);
            s1[4] = f2bf(f3.x); s1[5] = f2bf(f3.y); s1[6] = f2bf(f3.z); s1[7] = f2bf(f3.w);
            *(bf16x8*)&As[r * LDA + half * 16] = s0;
            *(bf16x8*)&As[r * LDA + half * 16 + 8] = s1;
        } else {
#pragma unroll
            for (int i = 0; i < 2; ++i) {
                int s = tid + i * 256, r = s >> 2, q = s & 3;
                int grow = m0 + r;
                int4 v = make_int4(0, 0, 0, 0);
                if (grow < Nn) v = *(const int4*)(Ab + (size_t)grow * 256 + k0 + q * 8);
                *(int4*)&As[r * LDA + q * 8] = v;
            }
        }
#pragma unroll
        for (int i = 0; i < BN / 64; ++i) {
            int s = tid + i * 256, c = s >> 2, q = s & 3;
            int4 v = *(const int4*)(Bt + (size_t)(col0 + c) * 256 + k0 + q * 8);
            *(int4*)&Bs[c * LDA + q * 8] = v;
        }
        __syncthreads();
        bf16x8 af[MREP], bfr[4];
#pragma unroll
        for (int m = 0; m < MREP; ++m)
            af[m] = *(const bf16x8*)&As[(wr_ * MROWS + m * 16 + lr) * LDA + lg * 8];
#pragma unroll
        for (int n = 0; n < 4; ++n)
            bfr[n] = *(const bf16x8*)&Bs[(wc * 64 + n * 16 + lr) * LDA + lg * 8];
#pragma unroll
        for (int m = 0; m < MREP; ++m)
#pragma unroll
            for (int n = 0; n < 4; ++n)
                acc[m][n] = __builtin_amdgcn_mfma_f32_16x16x32_bf16(af[m], bfr[n], acc[m][n], 0, 0, 0);
        __syncthreads();
    }

    int coln[4];
    float biasv[4], wlv[4] = {}, wrv[4] = {};
#pragma unroll
    for (int n = 0; n < 4; ++n) {
        coln[n] = col0 + wc * 64 + n * 16 + lr;
        biasv[n] = bias[coln[n]];
        if (FUSEA) { wlv[n] = wl[coln[n]]; wrv[n] = wr[coln[n]]; }
    }
    int head = (col0 + wc * 64) >> 6;
#pragma unroll
    for (int m = 0; m < MREP; ++m) {
#pragma unroll
        for (int e = 0; e < 4; ++e) {
            int row = m0 + wr_ * MROWS + m * 16 + lg * 4 + e;
            bool ok = row < Nn;
            float vv[4], p1 = 0.f, p2 = 0.f;
#pragma unroll
            for (int n = 0; n < 4; ++n) {
                float v = acc[m][n][e] + biasv[n];
                if (ADD) v += ok ? addp[(size_t)row * 64 + coln[n]] : 0.f;
                if (FUSEA) { p1 += v * wlv[n]; p2 += v * wrv[n]; }
                if (ELU) v = v > 0.f ? v : __expf(v) - 1.f;
                vv[n] = v;
            }
            if (FUSEA) {
#pragma unroll
                for (int o = 1; o < 16; o <<= 1) {
                    p1 += __shfl_xor(p1, o);
                    p2 += __shfl_xor(p2, o);
                }
                if (lr == 0 && ok) {
                    a1[(size_t)row * astride + head] = p1 + blp[head];
                    a2[(size_t)row * astride + head] = p2 + brp[head];
                }
            }
            if (ok) {
#pragma unroll
                for (int n = 0; n < 4; ++n) {
                    if (BF16OUT)
                        outb[(size_t)row * ostride + coln[n]] = f2bf(vv[n]);
                    else
                        outf[(size_t)row * ostride + coln[n]] = vv[n];
                }
            }
        }
    }
}

// ---------------- max pass (CSC walk), 4 nodes/wave; writes packed {a1, m} ----------------
__global__ __launch_bounds__(256) void maxpass4_k(const int* __restrict__ rowpd,
                                                  const int* __restrict__ cscsrc,
                                                  const float* __restrict__ a1,
                                                  const float* __restrict__ a2,
                                                  float2* __restrict__ pm4) {
    int tid = threadIdx.x;
    int node = blockIdx.x * 16 + (tid >> 4);
    if (node >= Nn) return;
    int l16 = tid & 15;
    int slot = l16 >> 2, h = l16 & 3;
    int r0 = rowpd[node], r1 = rowpd[node + 1];
    float a1v = a1[node * 4 + h];
    float m = 0.f;
    for (int i = r0 + slot; i < r1; i += 4) {
        int s = cscsrc[i];
        float v = a1v + a2[s * 4 + h];
        float a = v > 0.f ? v : 0.01f * v;
        m = fmaxf(m, a);
    }
    m = fmaxf(m, __shfl_xor(m, 4));
    m = fmaxf(m, __shfl_xor(m, 8));
    if (slot == 0) pm4[node * 4 + h] = make_float2(a1v, m);
}

__global__ __launch_bounds__(256) void maxpass1_k(const int* __restrict__ rowpd,
                                                  const int* __restrict__ cscsrc,
                                                  const float* __restrict__ a1,
                                                  const float* __restrict__ a2,
                                                  float2* __restrict__ pm2) {
    int tid = threadIdx.x;
    int node = blockIdx.x * 16 + (tid >> 4);
    if (node >= Nn) return;
    int slot = tid & 15;
    int r0 = rowpd[node], r1 = rowpd[node + 1];
    float a1v = a1[node];
    float m = 0.f;
    for (int i = r0 + slot; i < r1; i += 16) {
        float v = a1v + a2[cscsrc[i]];
        float a = v > 0.f ? v : 0.01f * v;
        m = fmaxf(m, a);
    }
#pragma unroll
    for (int o = 1; o < 16; o <<= 1) m = fmaxf(m, __shfl_xor(m, o));
    if (slot == 0) pm2[node] = make_float2(a1v, m);
}

// ---------------- sum pass (CSR walk), 4 nodes/wave; one pm gather/edge; stores 1/S ----------------
__global__ __launch_bounds__(256) void sumpass4_k(const int* __restrict__ rowps,
                                                  const int* __restrict__ csrdst,
                                                  const float2* __restrict__ pm4,
                                                  const float* __restrict__ a2,
                                                  float* __restrict__ eacsr,
                                                  float* __restrict__ Sinv) {
    int tid = threadIdx.x;
    int node = blockIdx.x * 16 + (tid >> 4);
    if (node >= Nn) return;
    int l16 = tid & 15;
    int slot = l16 >> 2, h = l16 & 3;
    int r0 = rowps[node], r1 = rowps[node + 1];
    float a2v = a2[node * 4 + h];
    float S = 0.f;
    for (int i = r0 + slot; i < r1; i += 4) {
        int d = csrdst[i];
        float2 pm = pm4[(size_t)d * 4 + h];
        float v = pm.x + a2v;
        float a = v > 0.f ? v : 0.01f * v;
        float ea = __expf(a - pm.y);
        eacsr[(size_t)i * 4 + h] = ea;
        S += ea;
    }
    S += __shfl_xor(S, 4);
    S += __shfl_xor(S, 8);
    if (slot == 0) Sinv[node * 4 + h] = 1.0f / S;
}

__global__ __launch_bounds__(256) void sumpass1_k(const int* __restrict__ rowps,
                                                  const int* __restrict__ csrdst,
                                                  const float2* __restrict__ pm2,
                                                  const float* __restrict__ a2,
                                                  float* __restrict__ eacsr,
                                                  float* __restrict__ Sinv) {
    int tid = threadIdx.x;
    int node = blockIdx.x * 16 + (tid >> 4);
    if (node >= Nn) return;
    int slot = tid & 15;
    int r0 = rowps[node], r1 = rowps[node + 1];
    float a2v = a2[node];
    float S = 0.f;
    for (int i = r0 + slot; i < r1; i += 16) {
        int d = csrdst[i];
        float2 pm = pm2[d];
        float v = pm.x + a2v;
        float a = v > 0.f ? v : 0.01f * v;
        float ea = __expf(a - pm.y);
        eacsr[i] = ea;
        S += ea;
    }
#pragma unroll
    for (int o = 1; o < 16; o <<= 1) S += __shfl_xor(S, o);
    if (slot == 0) Sinv[node] = 1.0f / S;
}

// ---------------- edge pass C (layer 1, 4 heads), 4-edge batched ----------------
__global__ __launch_bounds__(256) void edgeC4_k(const int* __restrict__ rowp,
                                                const int* __restrict__ cdst,
                                                const float* __restrict__ eacsr,
                                                const float* __restrict__ Sinv4,
                                                const ushort_t* __restrict__ ftb,
                                                ushort_t* __restrict__ lastb) {
    int node = blockIdx.x * 4 + (threadIdx.x >> 6);
    int lane = threadIdx.x & 63;
    if (node >= Nn) return;
    int h = lane >> 4;
    const ushort_t* ftl = ftb + lane * 4;
    int r0 = rowp[node], r1 = rowp[node + 1];
    float ax = 0.f, ay = 0.f, az = 0.f, aw = 0.f;
    int i = r0;
    for (; i + 4 <= r1; i += 4) {
        int d[4];
        float w[4];
        uint2 f[4];
#pragma unroll
        for (int j = 0; j < 4; ++j) d[j] = cdst[i + j];
#pragma unroll
        for (int j = 0; j < 4; ++j) w[j] = eacsr[(size_t)(i + j) * 4 + h];
#pragma unroll
        for (int j = 0; j < 4; ++j) f[j] = *(const uint2*)(ftl + (size_t)d[j] * 256);
#pragma unroll
        for (int j = 0; j < 4; ++j) w[j] *= Sinv4[d[j] * 4 + h];
#pragma unroll
        for (int j = 0; j < 4; ++j) {
            ax += w[j] * bflo(f[j].x);
            ay += w[j] * bfhi(f[j].x);
            az += w[j] * bflo(f[j].y);
            aw += w[j] * bfhi(f[j].y);
        }
    }
    for (; i < r1; ++i) {
        int d = cdst[i];
        float w = eacsr[(size_t)i * 4 + h] * Sinv4[d * 4 + h];
        uint2 f = *(const uint2*)(ftl + (size_t)d * 256);
        ax += w * bflo(f.x);
        ay += w * bfhi(f.x);
        az += w * bflo(f.y);
        aw += w * bfhi(f.y);
    }
    ax = ax > 0.f ? ax : __expf(ax) - 1.f;
    ay = ay > 0.f ? ay : __expf(ay) - 1.f;
    az = az > 0.f ? az : __expf(az) - 1.f;
    aw = aw > 0.f ? aw : __expf(aw) - 1.f;
    uint2 o2;
    o2.x = (unsigned)f2bf(ax) | ((unsigned)f2bf(ay) << 16);
    o2.y = (unsigned)f2bf(az) | ((unsigned)f2bf(aw) << 16);
    *(uint2*)(lastb + (size_t)node * 256 + lane * 4) = o2;
}

// ---------------- edge pass C (layer 2), 8-edge batched (4 per half-wave) ----------------
__global__ __launch_bounds__(256) void edgeC1_k(const int* __restrict__ rowp,
                                                const int* __restrict__ cdst,
                                                const float* __restrict__ ea,
                                                const float* __restrict__ Sinv2,
                                                const ushort_t* __restrict__ ftb2,
                                                float* __restrict__ outp) {
    int node = blockIdx.x * 4 + (threadIdx.x >> 6);
    int lane = threadIdx.x & 63;
    if (node >= Nn) return;
    int half = lane >> 5, l = lane & 31;
    const ushort_t* ftl = ftb2 + l * 2;
    int r0 = rowp[node], r1 = rowp[node + 1];
    float acc0 = 0.f, acc1 = 0.f;
    int i0 = r0;
    for (; i0 + 8 <= r1; i0 += 8) {
        int d[4];
        float w[4];
        unsigned f[4];
#pragma unroll
        for (int j = 0; j < 4; ++j) {
            int idx = i0 + 2 * j + half;
            d[j] = cdst[idx];
            w[j] = ea[idx];
        }
#pragma unroll
        for (int j = 0; j < 4; ++j) f[j] = *(const unsigned*)(ftl + (size_t)d[j] * 64);
#pragma unroll
        for (int j = 0; j < 4; ++j) w[j] *= Sinv2[d[j]];
#pragma unroll
        for (int j = 0; j < 4; ++j) {
            acc0 += w[j] * bflo(f[j]);
            acc1 += w[j] * bfhi(f[j]);
        }
    }
    for (; i0 < r1; i0 += 2) {
        int i = i0 + half;
        if (i < r1) {
            int d = cdst[i];
            float w = ea[i] * Sinv2[d];
            unsigned f = *(const unsigned*)(ftl + (size_t)d * 64);
            acc0 += w * bflo(f);
            acc1 += w * bfhi(f);
        }
    }
    acc0 += __shfl_xor(acc0, 32);
    acc1 += __shfl_xor(acc1, 32);
    if (lane < 32) {
        *(float2*)(outp + (size_t)node * 64 + l * 2) = make_float2(acc0, acc1);
    }
}

// ---------------- launch ----------------
extern "C" void kernel_launch(void* const* d_in, const int* in_sizes, int n_in,
                              void* d_out, int out_size, void* d_ws, size_t ws_size,
                              hipStream_t stream) {
    const float* features = (const float*)d_in[0];
    const int* src = (const int*)d_in[1];
    const int* dst = (const int*)d_in[2];
    const float* W_fc = (const float*)d_in[3];
    const float* b_fc = (const float*)d_in[4];
    const float* w_al = (const float*)d_in[5];
    const float* b_al = (const float*)d_in[6];
    const float* w_ar = (const float*)d_in[7];
    const float* b_ar = (const float*)d_in[8];
    const float* W_res = (const float*)d_in[9];
    const float* b_res = (const float*)d_in[10];
    float* out = (float*)d_out;
    char* ws = (char*)d_ws;

    int* rowps = (int*)(ws + O_ROWPS);
    int* rowpd = (int*)(ws + O_ROWPD);
    int* boff = (int*)(ws + O_BOFF);
    int* gcur = (int*)(ws + O_GCUR);
    int* csr_dst = (int*)(ws + O_CSRDST);
    int* csc_src = (int*)(ws + O_CSCSRC);
    int2* bufs = (int2*)(ws + O_BUFS);
    int2* bufd = (int2*)(ws + O_BUFD);
    ushort_t* ftb1 = (ushort_t*)(ws + O_FTB1);
    ushort_t* ftb2 = (ushort_t*)(ws + O_FTB2);
    ushort_t* lastb = (ushort_t*)(ws + O_LASTB);
    float* eacsr = (float*)(ws + O_EACSR);
    float2* pm4 = (float2*)(ws + O_PM4);
    float* S4 = (float*)(ws + O_S4);
    float* a1_4 = (float*)(ws + O_A14);
    float* a2_4 = (float*)(ws + O_A24);
    float2* pm2 = (float2*)(ws + O_PM2);
    float* S2 = (float*)(ws + O_S2);
    float* a1_2 = (float*)(ws + O_A12);
    float* a2_2 = (float*)(ws + O_A22);
    float* out2 = (float*)(ws + O_OUT2);
    float* ea_l2 = (float*)(ws + O_EAL2);
    ushort_t* Wt1 = (ushort_t*)(ws + O_WT1);
    ushort_t* Wt2 = (ushort_t*)(ws + O_WT2);
    ushort_t* WtR = (ushort_t*)(ws + O_WTR);

    // ---- weight convert/transpose (tiny) ----
    wcvt_k<<<384, 256, 0, stream>>>(W_fc, W_res, Wt1, Wt2, WtR);

    // ---- graph build: bucketed counting sort ----
    hipMemsetAsync(gcur, 0, 2 * NBUCK * 4, stream);
    p3_bin_k<<<NBLK3, 256, 0, stream>>>(src, dst, gcur, bufs, bufd);
    p2_scan_k<<<2, 512, 0, stream>>>(gcur, boff, rowps, rowpd);
    p4_fill_k<<<dim3(NBUCK, 2), 256, 0, stream>>>(gcur, boff, bufs, bufd,
                                                  rowps, rowpd, csr_dst, csc_src);

    const int GB = (Nn + 127) / 128;   // 782
    const int NW = (Nn + 3) / 4;       // 25000
    const int NW16 = (Nn + 15) / 16;   // 6250
    // ---- layer 1: MFMA GEMM, 2 column panels (features L3-resident) ----
    mgemm_k<0, 128, 2, 1, 0, 0, 1><<<dim3(GB, 2), 256, 0, stream>>>(
        features, nullptr, Wt1, b_fc, nullptr,
        ftb1, nullptr, 256, w_al, w_ar, b_al, b_ar, a1_4, a2_4, 4);
    maxpass4_k<<<NW16, 256, 0, stream>>>(rowpd, csc_src, a1_4, a2_4, pm4);
    sumpass4_k<<<NW16, 256, 0, stream>>>(rowps, csr_dst, pm4, a2_4, eacsr, S4);
    edgeC4_k<<<NW, 256, 0, stream>>>(rowps, csr_dst, eacsr, S4, ftb1, lastb);

    // ---- layer 2: head 4 (A = lastb bf16) ----
    mgemm_k<1, 64, 4, 1, 0, 0, 1><<<dim3(GB, 1), 256, 0, stream>>>(
        nullptr, lastb, Wt2, b_fc + 256, nullptr,
        ftb2, nullptr, 64, w_al + 256, w_ar + 256, b_al + 4, b_ar + 4,
        a1_2, a2_2, 1);
    maxpass1_k<<<NW16, 256, 0, stream>>>(rowpd, csc_src, a1_2, a2_2, pm2);
    sumpass1_k<<<NW16, 256, 0, stream>>>(rowps, csr_dst, pm2, a2_2, ea_l2, S2);
    edgeC1_k<<<NW, 256, 0, stream>>>(rowps, csr_dst, ea_l2, S2, ftb2, out2);

    // ---- final: elu(lastb @ WtR^T + b_res + out2) -> f32 out ----
    mgemm_k<1, 64, 4, 0, 1, 1, 0><<<dim3(GB, 1), 256, 0, stream>>>(
        nullptr, lastb, WtR, b_res, out2,
        nullptr, out, 64, nullptr, nullptr, nullptr, nullptr, nullptr, nullptr, 0);
}